// Round 1
// baseline (10306.319 us; speedup 1.0000x reference)
//
#include <hip/hip_runtime.h>
#include <hip/hip_bf16.h>
#include <cstdint>

typedef __hip_bfloat16 bf16;
typedef __attribute__((ext_vector_type(8))) short bf16x8v;   // 8 bf16 in 4 VGPRs
typedef __attribute__((ext_vector_type(4))) float f32x4;

#define TM1 64
#define BATCH 512
#define BELIEF 2048
#define STATE 256
#define ACTION 64
#define HIDDEN 2048
#define EMB 1024

// output offsets (elements) in d_out, per reference return order
#define OUT_BEL  ((size_t)0)
#define OUT_PST  ((size_t)67108864)   // prior_states
#define OUT_PMU  ((size_t)75497472)   // prior_means
#define OUT_PSD  ((size_t)83886080)   // prior_std_devs
#define OUT_QST  ((size_t)92274688)   // posterior_states
#define OUT_QMU  ((size_t)100663296)  // posterior_means
#define OUT_QSD  ((size_t)109051904)  // posterior_std_devs

__device__ __forceinline__ void gload_lds16(const bf16* g, bf16* l) {
  __builtin_amdgcn_global_load_lds(
      (const __attribute__((address_space(1))) unsigned int*)g,
      (__attribute__((address_space(3))) unsigned int*)l, 16, 0, 0);
}

// ---------------------------------------------------------------------------
// GEMM: C[M,N] = A[M,K](bf16,row) * Bt[N,K](bf16,row)^T + bias[N]
// MODE 0: C fp32.  MODE 1: C bf16 with relu.
// blockIdx.z==1 selects the second (A1,B1,bias1,C1) problem (same M,N,K).
// 256 threads, 2x2 waves, 16x16x32 MFMA, BK=64, m97-style global_load_lds.
// ---------------------------------------------------------------------------
template<int BM, int BN, int MODE>
__global__ __launch_bounds__(256)
void gemm_bt(const bf16* __restrict__ A0, const bf16* __restrict__ A1,
             const bf16* __restrict__ B0, const bf16* __restrict__ B1,
             const float* __restrict__ bias0, const float* __restrict__ bias1,
             void* __restrict__ C0, void* __restrict__ C1,
             int M, int N, int K)
{
  constexpr int BK = 64;
  constexpr int WMt = BM / 2, WNt = BN / 2;
  constexpr int MR = WMt / 16, NR = WNt / 16;

  const bf16* A = A0; const bf16* B = B0; const float* bias = bias0; void* Cv = C0;
  if (blockIdx.z) { A = A1; B = B1; bias = bias1; Cv = C1; }

  const int m0 = blockIdx.y * BM;
  const int n0 = blockIdx.x * BN;

  __shared__ __align__(16) bf16 sA[BM * BK];
  __shared__ __align__(16) bf16 sB[BN * BK];

  const int tid = threadIdx.x;
  const int lane = tid & 63;
  const int wid = tid >> 6;
  const int wm = wid >> 1, wn = wid & 1;
  const int lr = lane & 15;
  const int ko = (lane >> 4) * 8;

  f32x4 acc[MR][NR] = {};

  for (int k0 = 0; k0 < K; k0 += BK) {
    __syncthreads();   // previous tile fully consumed
    #pragma unroll
    for (int i = 0; i < BM * 8 / 256; ++i) {
      int c = i * 256 + tid;
      int row = c >> 3, koct = c & 7;            // BK=64 -> 8 x 16B chunks/row
      gload_lds16(A + (size_t)(m0 + row) * K + k0 + koct * 8, &sA[c * 8]);
    }
    #pragma unroll
    for (int i = 0; i < BN * 8 / 256; ++i) {
      int c = i * 256 + tid;
      int row = c >> 3, koct = c & 7;
      gload_lds16(B + (size_t)(n0 + row) * K + k0 + koct * 8, &sB[c * 8]);
    }
    __syncthreads();   // implies vmcnt(0): staged data visible

    #pragma unroll
    for (int kk = 0; kk < 2; ++kk) {
      bf16x8v af[MR], bfv[NR];
      #pragma unroll
      for (int m = 0; m < MR; ++m)
        af[m] = *(const bf16x8v*)&sA[(wm * WMt + m * 16 + lr) * BK + kk * 32 + ko];
      #pragma unroll
      for (int n = 0; n < NR; ++n)
        bfv[n] = *(const bf16x8v*)&sB[(wn * WNt + n * 16 + lr) * BK + kk * 32 + ko];
      #pragma unroll
      for (int m = 0; m < MR; ++m)
        #pragma unroll
        for (int n = 0; n < NR; ++n)
          acc[m][n] = __builtin_amdgcn_mfma_f32_16x16x32_bf16(af[m], bfv[n], acc[m][n], 0, 0, 0);
    }
  }

  // epilogue: C/D layout col=lane&15, row=(lane>>4)*4+reg
  const int r0 = (lane >> 4) * 4;
  #pragma unroll
  for (int m = 0; m < MR; ++m) {
    #pragma unroll
    for (int n = 0; n < NR; ++n) {
      int gc = n0 + wn * WNt + n * 16 + lr;
      float bv = bias[gc];
      #pragma unroll
      for (int r = 0; r < 4; ++r) {
        int gr = m0 + wm * WMt + m * 16 + r0 + r;
        float v = acc[m][n][r] + bv;
        if (MODE == 1) {
          ((bf16*)Cv)[(size_t)gr * N + gc] = __float2bfloat16(v > 0.f ? v : 0.f);
        } else {
          ((float*)Cv)[(size_t)gr * N + gc] = v;
        }
      }
    }
  }
}

// ---------------------------------------------------------------------------
// prep: transpose fp32 [K,N] -> bf16 [N,K]
// ---------------------------------------------------------------------------
__global__ void transpose_cvt(const float* __restrict__ src, bf16* __restrict__ dst,
                              int K, int N)
{
  __shared__ float t[32][33];
  int n0 = blockIdx.x * 32, k0 = blockIdx.y * 32;
  int tx = threadIdx.x, ty = threadIdx.y;
  #pragma unroll
  for (int i = 0; i < 32; i += 8)
    t[ty + i][tx] = src[(size_t)(k0 + ty + i) * N + n0 + tx];
  __syncthreads();
  #pragma unroll
  for (int i = 0; i < 32; i += 8)
    dst[(size_t)(n0 + ty + i) * K + k0 + tx] = __float2bfloat16(t[tx][ty + i]);
}

__global__ void init_belief(const float* __restrict__ prev_belief,
                            float* __restrict__ bf32, bf16* __restrict__ bb16)
{
  int i = blockIdx.x * 256 + threadIdx.x;
  float v = prev_belief[i];
  bf32[i] = v;
  bb16[i] = __float2bfloat16(v);
}

__global__ void xcat0_kernel(const float* __restrict__ prev_state,
                             const float* __restrict__ nt0,
                             const float* __restrict__ act0,
                             bf16* __restrict__ xcat)
{
  int idx = blockIdx.x * 256 + threadIdx.x;
  if (idx >= BATCH * (STATE + ACTION)) return;
  int b = idx / (STATE + ACTION);
  int c = idx - b * (STATE + ACTION);
  float v;
  if (c < STATE) v = prev_state[b * STATE + c] * nt0[b];
  else           v = act0[b * ACTION + (c - STATE)];
  xcat[idx] = __float2bfloat16(v);
}

__device__ __forceinline__ float sigmoidf_(float x) { return 1.f / (1.f + __expf(-x)); }

// GRU gate math + write belief (f32 carry, bf16 copy, d_out) + build posterior
// concat A = [belief_bf16 | obs_bf16]
__global__ void gru_ew(const float* __restrict__ gi, const float* __restrict__ gh,
                       float* __restrict__ belief_f32, bf16* __restrict__ belief_b16,
                       float* __restrict__ out_bel_t, bf16* __restrict__ hqcat,
                       const float* __restrict__ obs_t)
{
  int idx = blockIdx.x * 256 + threadIdx.x;   // 512*2048
  int b = idx >> 11;
  int c = idx & 2047;
  size_t base = (size_t)b * 3 * BELIEF;
  float ir = gi[base + c], iz = gi[base + BELIEF + c], in_ = gi[base + 2 * BELIEF + c];
  float hr = gh[base + c], hz = gh[base + BELIEF + c], hn  = gh[base + 2 * BELIEF + c];
  float r = sigmoidf_(ir + hr);
  float z = sigmoidf_(iz + hz);
  float n = tanhf(in_ + r * hn);
  float nb = (1.f - z) * n + z * belief_f32[idx];
  belief_f32[idx] = nb;
  bf16 v = __float2bfloat16(nb);
  belief_b16[idx] = v;
  out_bel_t[idx] = nb;
  hqcat[(size_t)b * (BELIEF + EMB) + c] = v;
  if (c < EMB)
    hqcat[(size_t)b * (BELIEF + EMB) + BELIEF + c] = __float2bfloat16(obs_t[(size_t)b * EMB + c]);
}

// posterior sample + outputs + (fused) next-step embed input [s*nt | a]
__global__ void post_ew(const float* __restrict__ yq, const float* __restrict__ eps,
                        float* __restrict__ o_mu, float* __restrict__ o_sd,
                        float* __restrict__ o_st,
                        const float* __restrict__ nt_next, const float* __restrict__ act_next,
                        bf16* __restrict__ xcat, int make_xcat)
{
  int idx = blockIdx.x * 256 + threadIdx.x;   // 512*256
  int b = idx >> 8;
  int j = idx & 255;
  float loc = yq[(size_t)b * 512 + j];
  float raw = yq[(size_t)b * 512 + 256 + j];
  float sp = (raw > 20.f) ? raw : log1pf(__expf(raw));
  float scale = sp + 0.1f;
  float st = loc + scale * eps[idx];
  o_mu[idx] = loc;
  o_sd[idx] = scale;
  o_st[idx] = st;
  if (make_xcat) {
    xcat[(size_t)b * (STATE + ACTION) + j] = __float2bfloat16(st * nt_next[b]);
    if (j < ACTION)
      xcat[(size_t)b * (STATE + ACTION) + STATE + j] =
          __float2bfloat16(act_next[(size_t)b * ACTION + j]);
  }
}

__global__ void cvt_f32_bf16(const float* __restrict__ src, bf16* __restrict__ dst, int n)
{
  int i = blockIdx.x * 256 + threadIdx.x;
  if (i < n) dst[i] = __float2bfloat16(src[i]);
}

__global__ void prior_ew(const float* __restrict__ yp, const float* __restrict__ eps,
                         float* __restrict__ o_mu, float* __restrict__ o_sd,
                         float* __restrict__ o_st)
{
  int idx = blockIdx.x * 256 + threadIdx.x;   // rows*256
  int r = idx >> 8;
  int j = idx & 255;
  float loc = yp[(size_t)r * 512 + j];
  float raw = yp[(size_t)r * 512 + 256 + j];
  float sp = (raw > 20.f) ? raw : log1pf(__expf(raw));
  float scale = sp + 0.1f;
  o_mu[idx] = loc;
  o_sd[idx] = scale;
  o_st[idx] = loc + scale * eps[idx];
}

// ---------------------------------------------------------------------------
extern "C" void kernel_launch(void* const* d_in, const int* in_sizes, int n_in,
                              void* d_out, int out_size, void* d_ws, size_t ws_size,
                              hipStream_t stream)
{
  (void)in_sizes; (void)n_in; (void)out_size; (void)ws_size;
  const float* prev_state = (const float*)d_in[0];
  const float* actions    = (const float*)d_in[1];
  const float* prev_belief= (const float*)d_in[2];
  const float* obs_emb    = (const float*)d_in[3];
  const float* nonterm    = (const float*)d_in[4];
  const float* W_embed    = (const float*)d_in[5];
  const float* b_embed    = (const float*)d_in[6];
  const float* Wi         = (const float*)d_in[7];
  const float* bi         = (const float*)d_in[8];
  const float* Wh         = (const float*)d_in[9];
  const float* bh         = (const float*)d_in[10];
  const float* W1         = (const float*)d_in[11];
  const float* b1         = (const float*)d_in[12];
  const float* W2         = (const float*)d_in[13];
  const float* b2         = (const float*)d_in[14];
  const float* W1p        = (const float*)d_in[15];
  const float* b1p        = (const float*)d_in[16];
  const float* W2p        = (const float*)d_in[17];
  const float* b2p        = (const float*)d_in[18];
  const float* eps_p      = (const float*)d_in[19];
  const float* eps_q      = (const float*)d_in[20];
  float* out = (float*)d_out;

  char* ws = (char*)d_ws;
  size_t off = 0;
  auto alloc = [&](size_t bytes) -> char* {
    char* p = ws + off;
    off = (off + bytes + 255) & ~(size_t)255;
    return p;
  };
  bf16* WembT = (bf16*)alloc((size_t)2048 * 320 * 2);
  bf16* WiT   = (bf16*)alloc((size_t)6144 * 2048 * 2);
  bf16* WhT   = (bf16*)alloc((size_t)6144 * 2048 * 2);
  bf16* W1T   = (bf16*)alloc((size_t)2048 * 2048 * 2);
  bf16* W2T   = (bf16*)alloc((size_t)512 * 2048 * 2);
  bf16* W1pT  = (bf16*)alloc((size_t)2048 * 3072 * 2);
  bf16* W2pT  = (bf16*)alloc((size_t)512 * 2048 * 2);
  float* belief_f32 = (float*)alloc((size_t)BATCH * BELIEF * 4);
  bf16*  belief_b16 = (bf16*)alloc((size_t)BATCH * BELIEF * 2);
  bf16*  xcat       = (bf16*)alloc((size_t)BATCH * (STATE + ACTION) * 2);
  bf16*  hidden     = (bf16*)alloc((size_t)BATCH * BELIEF * 2);
  float* gi         = (float*)alloc((size_t)BATCH * 3 * BELIEF * 4);
  float* gh         = (float*)alloc((size_t)BATCH * 3 * BELIEF * 4);
  bf16*  hqcat      = (bf16*)alloc((size_t)BATCH * (BELIEF + EMB) * 2);
  bf16*  hq         = (bf16*)alloc((size_t)BATCH * HIDDEN * 2);
  float* yq         = (float*)alloc((size_t)BATCH * 512 * 4);
  bf16*  belA       = (bf16*)alloc((size_t)4096 * BELIEF * 2);
  bf16*  hp         = (bf16*)alloc((size_t)4096 * HIDDEN * 2);
  float* yp         = (float*)alloc((size_t)4096 * 512 * 4);

  dim3 tb(32, 8);
  // weight transposes: src [K,N] -> dst [N,K]
  transpose_cvt<<<dim3(2048/32, 320/32),  tb, 0, stream>>>(W_embed, WembT, 320, 2048);
  transpose_cvt<<<dim3(6144/32, 2048/32), tb, 0, stream>>>(Wi, WiT, 2048, 6144);
  transpose_cvt<<<dim3(6144/32, 2048/32), tb, 0, stream>>>(Wh, WhT, 2048, 6144);
  transpose_cvt<<<dim3(2048/32, 2048/32), tb, 0, stream>>>(W1, W1T, 2048, 2048);
  transpose_cvt<<<dim3(512/32, 2048/32),  tb, 0, stream>>>(W2, W2T, 2048, 512);
  transpose_cvt<<<dim3(2048/32, 3072/32), tb, 0, stream>>>(W1p, W1pT, 3072, 2048);
  transpose_cvt<<<dim3(512/32, 2048/32),  tb, 0, stream>>>(W2p, W2pT, 2048, 512);

  init_belief<<<(BATCH * BELIEF) / 256, 256, 0, stream>>>(prev_belief, belief_f32, belief_b16);
  xcat0_kernel<<<(BATCH * (STATE + ACTION) + 255) / 256, 256, 0, stream>>>(
      prev_state, nonterm, actions, xcat);

  for (int t = 0; t < TM1; ++t) {
    // hidden = relu(xcat @ W_embed + b_embed)   [512,2048] K=320
    gemm_bt<128, 128, 1><<<dim3(16, 4, 1), 256, 0, stream>>>(
        xcat, nullptr, WembT, nullptr, b_embed, nullptr, hidden, nullptr,
        512, 2048, 320);
    // gi = hidden @ Wi + bi ; gh = belief @ Wh + bh   [512,6144] K=2048
    gemm_bt<128, 128, 0><<<dim3(48, 4, 2), 256, 0, stream>>>(
        hidden, belief_b16, WiT, WhT, bi, bh, gi, gh,
        512, 6144, 2048);
    gru_ew<<<(BATCH * BELIEF) / 256, 256, 0, stream>>>(
        gi, gh, belief_f32, belief_b16,
        out + OUT_BEL + (size_t)t * BATCH * BELIEF,
        hqcat, obs_emb + (size_t)t * BATCH * EMB);
    // hq = relu(hqcat @ W1p + b1p)   [512,2048] K=3072
    gemm_bt<64, 128, 1><<<dim3(16, 8, 1), 256, 0, stream>>>(
        hqcat, nullptr, W1pT, nullptr, b1p, nullptr, hq, nullptr,
        512, 2048, 3072);
    // yq = hq @ W2p + b2p   [512,512] K=2048
    gemm_bt<64, 64, 0><<<dim3(8, 8, 1), 256, 0, stream>>>(
        hq, nullptr, W2pT, nullptr, b2p, nullptr, yq, nullptr,
        512, 512, 2048);
    post_ew<<<(BATCH * STATE) / 256, 256, 0, stream>>>(
        yq, eps_q + (size_t)t * BATCH * STATE,
        out + OUT_QMU + (size_t)t * BATCH * STATE,
        out + OUT_QSD + (size_t)t * BATCH * STATE,
        out + OUT_QST + (size_t)t * BATCH * STATE,
        nonterm + (size_t)(t + 1) * BATCH,
        actions + (size_t)(t + 1) * BATCH * ACTION,
        xcat, (t < TM1 - 1) ? 1 : 0);
  }

  // batched prior over all T*B rows, in 8 chunks of 4096 rows
  for (int c = 0; c < 8; ++c) {
    const float* belsrc = out + OUT_BEL + (size_t)c * 4096 * BELIEF;
    cvt_f32_bf16<<<(4096 * BELIEF) / 256, 256, 0, stream>>>(belsrc, belA, 4096 * BELIEF);
    gemm_bt<128, 128, 1><<<dim3(16, 32, 1), 256, 0, stream>>>(
        belA, nullptr, W1T, nullptr, b1, nullptr, hp, nullptr,
        4096, 2048, 2048);
    gemm_bt<128, 64, 0><<<dim3(8, 32, 1), 256, 0, stream>>>(
        hp, nullptr, W2T, nullptr, b2, nullptr, yp, nullptr,
        4096, 512, 2048);
    prior_ew<<<(4096 * 256) / 256, 256, 0, stream>>>(
        yp, eps_p + (size_t)c * 4096 * STATE,
        out + OUT_PMU + (size_t)c * 4096 * STATE,
        out + OUT_PSD + (size_t)c * 4096 * STATE,
        out + OUT_PST + (size_t)c * 4096 * STATE);
  }
}